// Round 1
// baseline (1516.214 us; speedup 1.0000x reference)
//
#include <hip/hip_runtime.h>
#include <math.h>

// MLA: x[2,2048,1024] fp32. B=2, N=2048, D=1024, L=512, H=16, Dh=64.
// Stages:
//  q   = x @ Wq * 0.125                    [4096,1024]
//  kv  = x @ Wkv                           [4096,2048]
//  k   = relu(kv[:, :1024] @ Wk1) @ Wk2    [4096,1024]
//  v   = relu(kv[:, 1024:] @ Wv1) @ Wv2    [4096,1024]
//  attn = flash(q,k,v) per (b,h)           [4096,1024]
//  out = attn @ Wo + bo                    [4096,1024]

#define TILE 64
#define BK 16

// C[m,n] = alpha * sum_k A[m,k]*W[k,n]  (+bias) (relu?)
// grid: (N/64, M/64), block 256
__global__ __launch_bounds__(256) void gemm_f32_kernel(
    const float* __restrict__ A, int lda,
    const float* __restrict__ W, int ldw,
    float* __restrict__ C, int ldc,
    int K, const float* __restrict__ bias,
    float alpha, int relu)
{
    const int n0 = blockIdx.x * TILE;
    const int m0 = blockIdx.y * TILE;
    const int t  = threadIdx.x;
    const int tx = t & 15;
    const int ty = t >> 4;

    __shared__ float As[BK][TILE + 4];  // stride 68 floats: 16B-aligned rows, breaks pow2 banks
    __shared__ float Ws[BK][TILE];

    float acc[4][4] = {};

    const int arow = t >> 2;         // 0..63
    const int akq  = (t & 3) * 4;    // 0,4,8,12
    const int wrow = t >> 4;         // 0..15
    const int wcol = (t & 15) * 4;   // 0..60

    for (int k0 = 0; k0 < K; k0 += BK) {
        float4 av = *(const float4*)&A[(m0 + arow) * lda + k0 + akq];
        float4 wv = *(const float4*)&W[(k0 + wrow) * ldw + n0 + wcol];
        As[akq + 0][arow] = av.x;
        As[akq + 1][arow] = av.y;
        As[akq + 2][arow] = av.z;
        As[akq + 3][arow] = av.w;
        *(float4*)&Ws[wrow][wcol] = wv;
        __syncthreads();
#pragma unroll
        for (int k = 0; k < BK; ++k) {
            float4 a = *(const float4*)&As[k][ty * 4];
            float4 b = *(const float4*)&Ws[k][tx * 4];
            float aa[4] = {a.x, a.y, a.z, a.w};
            float bb[4] = {b.x, b.y, b.z, b.w};
#pragma unroll
            for (int i = 0; i < 4; ++i)
#pragma unroll
                for (int j = 0; j < 4; ++j)
                    acc[i][j] = fmaf(aa[i], bb[j], acc[i][j]);
        }
        __syncthreads();
    }

#pragma unroll
    for (int i = 0; i < 4; ++i) {
        const int row = m0 + ty * 4 + i;
        float4 o;
        float vals[4];
#pragma unroll
        for (int j = 0; j < 4; ++j) {
            float v = acc[i][j] * alpha;
            if (bias) v += bias[n0 + tx * 4 + j];
            if (relu) v = fmaxf(v, 0.0f);
            vals[j] = v;
        }
        o.x = vals[0]; o.y = vals[1]; o.z = vals[2]; o.w = vals[3];
        *(float4*)&C[row * ldc + n0 + tx * 4] = o;
    }
}

// Flash attention fp32. grid: (N/64, H, B), block 256.
// Q pre-scaled by 0.125 (folded into q GEMM alpha).
__global__ __launch_bounds__(256) void flash_f32_kernel(
    const float* __restrict__ Q, const float* __restrict__ K,
    const float* __restrict__ V, float* __restrict__ O)
{
    const int N = 2048, D = 1024;
    const int qt = blockIdx.x;
    const int h  = blockIdx.y;
    const int b  = blockIdx.z;
    const int t  = threadIdx.x;
    const int tx = t & 15;
    const int ty = t >> 4;

    __shared__ float Qs[64][68];    // [qrow][d]
    __shared__ float KVs[64][68];   // [kvrow][d] — K during S, reloaded with V for PV
    __shared__ float Pt[64][66];    // transposed scores [kvcol][qrow]
    __shared__ float m_s[64], l_s[64], alpha_s[64];

    const int lrow = t >> 4;         // 0..15
    const int lcol = (t & 15) * 4;   // 0..60

    const int qbase = (b * 2048 + qt * 64) * D + h * 64;
#pragma unroll
    for (int i = 0; i < 4; ++i)
        *(float4*)&Qs[lrow + i * 16][lcol] =
            *(const float4*)&Q[qbase + (lrow + i * 16) * D + lcol];
    if (t < 64) { m_s[t] = -1e30f; l_s[t] = 0.0f; }

    float acc[4][4] = {};

    for (int j = 0; j < N; j += 64) {
        __syncthreads();   // prev PV done (and Qs/m/l ready on first iter)
        const int kbase = (b * 2048 + j) * D + h * 64;
#pragma unroll
        for (int i = 0; i < 4; ++i)
            *(float4*)&KVs[lrow + i * 16][lcol] =
                *(const float4*)&K[kbase + (lrow + i * 16) * D + lcol];
        __syncthreads();

        // S = Q @ K^T  (rows 4ty+i, cols 4tx+c), write transposed into Pt
        float s[4][4] = {};
#pragma unroll 4
        for (int d = 0; d < 64; d += 4) {
            float4 qv[4], kk[4];
#pragma unroll
            for (int i = 0; i < 4; ++i) qv[i] = *(const float4*)&Qs[ty * 4 + i][d];
#pragma unroll
            for (int i = 0; i < 4; ++i) kk[i] = *(const float4*)&KVs[tx * 4 + i][d];
#pragma unroll
            for (int i = 0; i < 4; ++i)
#pragma unroll
                for (int c = 0; c < 4; ++c)
                    s[i][c] += qv[i].x * kk[c].x + qv[i].y * kk[c].y +
                               qv[i].z * kk[c].z + qv[i].w * kk[c].w;
        }
#pragma unroll
        for (int i = 0; i < 4; ++i)
#pragma unroll
            for (int c = 0; c < 4; ++c)
                Pt[tx * 4 + c][ty * 4 + i] = s[i][c];
        __syncthreads();   // Pt ready; KVs free

        // load V into KVs while wave0 does softmax (independent buffers)
#pragma unroll
        for (int i = 0; i < 4; ++i)
            *(float4*)&KVs[lrow + i * 16][lcol] =
                *(const float4*)&V[kbase + (lrow + i * 16) * D + lcol];
        if (t < 64) {
            float m = m_s[t];
            float mj = -1e30f;
            for (int c = 0; c < 64; ++c) mj = fmaxf(mj, Pt[c][t]);
            float mnew = fmaxf(m, mj);
            float al = __expf(m - mnew);
            float sum = 0.0f;
            for (int c = 0; c < 64; ++c) {
                float p = __expf(Pt[c][t] - mnew);
                Pt[c][t] = p;
                sum += p;
            }
            m_s[t] = mnew;
            l_s[t] = l_s[t] * al + sum;
            alpha_s[t] = al;
        }
        __syncthreads();   // V + probs + alpha ready

        float al[4];
#pragma unroll
        for (int i = 0; i < 4; ++i) al[i] = alpha_s[ty * 4 + i];
#pragma unroll
        for (int i = 0; i < 4; ++i)
#pragma unroll
            for (int c = 0; c < 4; ++c)
                acc[i][c] *= al[i];

#pragma unroll 8
        for (int c = 0; c < 64; ++c) {
            float4 vv = *(const float4*)&KVs[c][tx * 4];
            float p[4];
#pragma unroll
            for (int i = 0; i < 4; ++i) p[i] = Pt[c][ty * 4 + i];
#pragma unroll
            for (int i = 0; i < 4; ++i) {
                acc[i][0] = fmaf(p[i], vv.x, acc[i][0]);
                acc[i][1] = fmaf(p[i], vv.y, acc[i][1]);
                acc[i][2] = fmaf(p[i], vv.z, acc[i][2]);
                acc[i][3] = fmaf(p[i], vv.w, acc[i][3]);
            }
        }
    }

    float rl[4];
#pragma unroll
    for (int i = 0; i < 4; ++i) rl[i] = 1.0f / l_s[ty * 4 + i];
    const int obase = (b * 2048 + qt * 64) * D + h * 64;
#pragma unroll
    for (int i = 0; i < 4; ++i) {
        float4 o;
        o.x = acc[i][0] * rl[i];
        o.y = acc[i][1] * rl[i];
        o.z = acc[i][2] * rl[i];
        o.w = acc[i][3] * rl[i];
        *(float4*)&O[obase + (ty * 4 + i) * D + tx * 4] = o;
    }
}

extern "C" void kernel_launch(void* const* d_in, const int* in_sizes, int n_in,
                              void* d_out, int out_size, void* d_ws, size_t ws_size,
                              hipStream_t stream) {
    const float* x   = (const float*)d_in[0];
    const float* Wq  = (const float*)d_in[1];
    const float* Wkv = (const float*)d_in[2];
    const float* Wk1 = (const float*)d_in[3];
    const float* Wk2 = (const float*)d_in[4];
    const float* Wv1 = (const float*)d_in[5];
    const float* Wv2 = (const float*)d_in[6];
    const float* Wo  = (const float*)d_in[7];
    const float* bo  = (const float*)d_in[8];
    float* out = (float*)d_out;

    float* ws   = (float*)d_ws;
    float* q    = ws;                      // 4096*1024 = 16MB
    float* kv   = ws + 4  * 1024 * 1024;   // 4096*2048 = 32MB
    float* kbuf = ws + 12 * 1024 * 1024;   // 16MB
    float* vbuf = ws + 16 * 1024 * 1024;   // 16MB
    float* tmp  = ws + 20 * 1024 * 1024;   // 4096*512 = 8MB  (total 88MB)
    float* attn = kv;                      // kv dead after k/v computed

    dim3 blk(256);
    const float scale = 0.125f;  // Dh^-0.5

    // q = x @ Wq * scale
    gemm_f32_kernel<<<dim3(16, 64), blk, 0, stream>>>(x, 1024, Wq, 1024, q, 1024, 1024, nullptr, scale, 0);
    // kv = x @ Wkv
    gemm_f32_kernel<<<dim3(32, 64), blk, 0, stream>>>(x, 1024, Wkv, 2048, kv, 2048, 1024, nullptr, 1.0f, 0);
    // k1 = relu(kv[:, :1024] @ Wk1)
    gemm_f32_kernel<<<dim3(8, 64),  blk, 0, stream>>>(kv, 2048, Wk1, 512, tmp, 512, 1024, nullptr, 1.0f, 1);
    // k = k1 @ Wk2
    gemm_f32_kernel<<<dim3(16, 64), blk, 0, stream>>>(tmp, 512, Wk2, 1024, kbuf, 1024, 512, nullptr, 1.0f, 0);
    // v1 = relu(kv[:, 1024:] @ Wv1)
    gemm_f32_kernel<<<dim3(8, 64),  blk, 0, stream>>>(kv + 1024, 2048, Wv1, 512, tmp, 512, 1024, nullptr, 1.0f, 1);
    // v = v1 @ Wv2
    gemm_f32_kernel<<<dim3(16, 64), blk, 0, stream>>>(tmp, 512, Wv2, 1024, vbuf, 1024, 512, nullptr, 1.0f, 0);
    // attention
    flash_f32_kernel<<<dim3(32, 16, 2), blk, 0, stream>>>(q, kbuf, vbuf, attn);
    // out = attn @ Wo + bo
    gemm_f32_kernel<<<dim3(16, 64), blk, 0, stream>>>(attn, 1024, Wo, 1024, out, 1024, 1024, bo, 1.0f, 0);
}

// Round 2
// 436.878 us; speedup vs baseline: 3.4706x; 3.4706x over previous
//
#include <hip/hip_runtime.h>
#include <stdint.h>

// MLA bf16-MFMA pipeline. B=2, N=2048, D=1024, L=512, H=16, Dh=64.
// All GEMMs: A[M][K] bf16 row-major x Bt[N][K] bf16 row-major (weights
// pre-transposed+converted), MFMA f32_16x16x32_bf16, m97 structure.

typedef __attribute__((ext_vector_type(8))) __bf16 bf16x8;
typedef __attribute__((ext_vector_type(4))) float f32x4;

__device__ inline unsigned short f2bfu(float f) {
    __bf16 b = (__bf16)f;
    return __builtin_bit_cast(unsigned short, b);
}

__device__ inline void load_lds16(const void* g, void* l) {
    __builtin_amdgcn_global_load_lds(
        (const __attribute__((address_space(1))) uint32_t*)g,
        (__attribute__((address_space(3))) uint32_t*)l, 16, 0, 0);
}

__device__ inline f32x4 mfma_bf16(bf16x8 a, bf16x8 b, f32x4 c) {
    return __builtin_amdgcn_mfma_f32_16x16x32_bf16(a, b, c, 0, 0, 0);
}

// ---------------- prep kernels ----------------

// fp32 -> bf16, n multiple of 1024
__global__ __launch_bounds__(256) void cvt_x_kernel(
    const float* __restrict__ src, unsigned short* __restrict__ dst)
{
    int i = (blockIdx.x * 256 + threadIdx.x) * 4;
    float4 v = *(const float4*)&src[i];
    ushort4 o;
    o.x = f2bfu(v.x); o.y = f2bfu(v.y); o.z = f2bfu(v.z); o.w = f2bfu(v.w);
    *(ushort4*)&dst[i] = o;
}

// src f32 [R][C] -> dst bf16 [C][R]; R,C multiples of 64. grid (C/64, R/64)
__global__ __launch_bounds__(256) void transpose_w_kernel(
    const float* __restrict__ src, unsigned short* __restrict__ dst, int R, int C)
{
    __shared__ float tile[64][65];
    int c0 = blockIdx.x * 64, r0 = blockIdx.y * 64;
    int t = threadIdx.x;
    int col = t & 63, rr = t >> 6;
#pragma unroll
    for (int i = 0; i < 16; ++i)
        tile[rr + i * 4][col] = src[(size_t)(r0 + rr + i * 4) * C + c0 + col];
    __syncthreads();
#pragma unroll
    for (int i = 0; i < 16; ++i) {
        int r2 = rr + i * 4;
        dst[(size_t)(c0 + r2) * R + r0 + col] = f2bfu(tile[col][r2]);
    }
}

// v[b][n][h*64+d] bf16 -> vt[(b*16+h)*64+d][n] bf16. grid (2048/64, 32)
__global__ __launch_bounds__(256) void transpose_v_kernel(
    const unsigned short* __restrict__ v, unsigned short* __restrict__ vt)
{
    __shared__ unsigned short tile[64][65];
    int n0 = blockIdx.x * 64, bh = blockIdx.y;
    int b = bh >> 4, h = bh & 15;
    int t = threadIdx.x;
    int r = t >> 3, c = t & 7;
#pragma unroll
    for (int p = 0; p < 2; ++p) {
        int row = r + p * 32;
        const unsigned short* src = v + (size_t)(b * 2048 + n0 + row) * 1024 + h * 64 + c * 8;
        ushort4 a = *(const ushort4*)src;
        ushort4 b4 = *(const ushort4*)(src + 4);
        tile[row][c * 8 + 0] = a.x;  tile[row][c * 8 + 1] = a.y;
        tile[row][c * 8 + 2] = a.z;  tile[row][c * 8 + 3] = a.w;
        tile[row][c * 8 + 4] = b4.x; tile[row][c * 8 + 5] = b4.y;
        tile[row][c * 8 + 6] = b4.z; tile[row][c * 8 + 7] = b4.w;
    }
    __syncthreads();
#pragma unroll
    for (int p = 0; p < 2; ++p) {
        int d = r + p * 32;
        ushort4 o0, o1;
        o0.x = tile[c * 8 + 0][d]; o0.y = tile[c * 8 + 1][d];
        o0.z = tile[c * 8 + 2][d]; o0.w = tile[c * 8 + 3][d];
        o1.x = tile[c * 8 + 4][d]; o1.y = tile[c * 8 + 5][d];
        o1.z = tile[c * 8 + 6][d]; o1.w = tile[c * 8 + 7][d];
        unsigned short* dp = vt + (size_t)(bh * 64 + d) * 2048 + n0 + c * 8;
        *(ushort4*)dp = o0;
        *(ushort4*)(dp + 4) = o1;
    }
}

// ---------------- bf16 MFMA GEMM (m97 structure) ----------------
// C[M][N] = alpha * A[M][K] @ Bt[N][K]^T (+bias)(relu). 128x128 tile, BK=32.
// grid (N/128, M/128), block 256.
__global__ __launch_bounds__(256) void gemm_bf16_kernel(
    const unsigned short* __restrict__ A, int lda,
    const unsigned short* __restrict__ Bt, int ldb,
    void* __restrict__ C, int ldc,
    int K, const float* __restrict__ bias,
    float alpha, int relu, int out_f32)
{
    __shared__ unsigned short Als[128 * 32];
    __shared__ unsigned short Bls[128 * 32];
    int t = threadIdx.x;
    int lane = t & 63, w = t >> 6;
    int n0 = blockIdx.x * 128, m0 = blockIdx.y * 128;
    int wm = (w & 1) * 64, wn = (w >> 1) * 64;
    int lrow = lane & 15, quad = lane >> 4;

    f32x4 acc[4][4];
    f32x4 z = {0.f, 0.f, 0.f, 0.f};
#pragma unroll
    for (int i = 0; i < 4; ++i)
#pragma unroll
        for (int j = 0; j < 4; ++j) acc[i][j] = z;

    int c0 = t, c1 = t + 256;
    const unsigned short* ag0 = A + (size_t)(m0 + (c0 >> 2)) * lda + (c0 & 3) * 8;
    const unsigned short* ag1 = A + (size_t)(m0 + (c1 >> 2)) * lda + (c1 & 3) * 8;
    const unsigned short* bg0 = Bt + (size_t)(n0 + (c0 >> 2)) * ldb + (c0 & 3) * 8;
    const unsigned short* bg1 = Bt + (size_t)(n0 + (c1 >> 2)) * ldb + (c1 & 3) * 8;

    for (int k0 = 0; k0 < K; k0 += 32) {
        __syncthreads();
        load_lds16(ag0 + k0, &Als[c0 * 8]);
        load_lds16(ag1 + k0, &Als[c1 * 8]);
        load_lds16(bg0 + k0, &Bls[c0 * 8]);
        load_lds16(bg1 + k0, &Bls[c1 * 8]);
        __syncthreads();

        bf16x8 af[4], bfr[4];
#pragma unroll
        for (int mi = 0; mi < 4; ++mi)
            af[mi] = *(const bf16x8*)&Als[(wm + mi * 16 + lrow) * 32 + quad * 8];
#pragma unroll
        for (int ni = 0; ni < 4; ++ni)
            bfr[ni] = *(const bf16x8*)&Bls[(wn + ni * 16 + lrow) * 32 + quad * 8];
#pragma unroll
        for (int mi = 0; mi < 4; ++mi)
#pragma unroll
            for (int ni = 0; ni < 4; ++ni)
                acc[mi][ni] = mfma_bf16(af[mi], bfr[ni], acc[mi][ni]);
    }

#pragma unroll
    for (int mi = 0; mi < 4; ++mi)
#pragma unroll
        for (int ni = 0; ni < 4; ++ni)
#pragma unroll
            for (int r = 0; r < 4; ++r) {
                int row = m0 + wm + mi * 16 + quad * 4 + r;
                int col = n0 + wn + ni * 16 + lrow;
                float v = acc[mi][ni][r] * alpha;
                if (bias) v += bias[col];
                if (relu) v = fmaxf(v, 0.0f);
                if (out_f32) ((float*)C)[(size_t)row * ldc + col] = v;
                else ((unsigned short*)C)[(size_t)row * ldc + col] = f2bfu(v);
            }
}

// ---------------- MFMA flash attention ----------------
// Q,K: bf16 [4096][1024] (head-interleaved); Vt: bf16 [32*64][2048].
// grid (2048/64, 32), block 256 (4 waves). Wave w owns Q rows w*16..w*16+15.
__global__ __launch_bounds__(256) void flash_mfma_kernel(
    const unsigned short* __restrict__ Q, const unsigned short* __restrict__ K,
    const unsigned short* __restrict__ Vt, unsigned short* __restrict__ O)
{
    __shared__ unsigned short Kls[64 * 64];
    __shared__ unsigned short Vls[64 * 64];
    __shared__ float Pls[4][16 * 68];

    int q0 = blockIdx.x * 64, bh = blockIdx.y;
    int b = bh >> 4, h = bh & 15;
    int t = threadIdx.x;
    int lane = t & 63, w = t >> 6;
    int lrow = lane & 15, quad = lane >> 4;

    // Q fragments in registers (A-layout, rows w*16+lrow)
    const unsigned short* qrow = Q + (size_t)(b * 2048 + q0 + w * 16 + lrow) * 1024 + h * 64;
    bf16x8 qf0 = *(const bf16x8*)&qrow[quad * 8];
    bf16x8 qf1 = *(const bf16x8*)&qrow[32 + quad * 8];

    f32x4 z = {0.f, 0.f, 0.f, 0.f};
    f32x4 acco[4];
#pragma unroll
    for (int i = 0; i < 4; ++i) acco[i] = z;
    float m_run[4] = {-1e30f, -1e30f, -1e30f, -1e30f};
    float l_run[4] = {0.f, 0.f, 0.f, 0.f};

    int c0 = t, c1 = t + 256;
    const unsigned short* kg0 = K + (size_t)(b * 2048 + (c0 >> 3)) * 1024 + h * 64 + (c0 & 7) * 8;
    const unsigned short* kg1 = K + (size_t)(b * 2048 + (c1 >> 3)) * 1024 + h * 64 + (c1 & 7) * 8;
    const unsigned short* vg0 = Vt + (size_t)(bh * 64 + (c0 >> 3)) * 2048 + (c0 & 7) * 8;
    const unsigned short* vg1 = Vt + (size_t)(bh * 64 + (c1 >> 3)) * 2048 + (c1 & 7) * 8;

    for (int kt = 0; kt < 2048; kt += 64) {
        __syncthreads();
        load_lds16(kg0 + (size_t)kt * 1024, &Kls[c0 * 8]);
        load_lds16(kg1 + (size_t)kt * 1024, &Kls[c1 * 8]);
        load_lds16(vg0 + kt, &Vls[c0 * 8]);
        load_lds16(vg1 + kt, &Vls[c1 * 8]);
        __syncthreads();

        // S = Q K^T : 16 rows (this wave) x 64 kv cols
        f32x4 s[4];
#pragma unroll
        for (int nt = 0; nt < 4; ++nt) {
            s[nt] = z;
            bf16x8 k0 = *(const bf16x8*)&Kls[(nt * 16 + lrow) * 64 + quad * 8];
            bf16x8 k1 = *(const bf16x8*)&Kls[(nt * 16 + lrow) * 64 + 32 + quad * 8];
            s[nt] = mfma_bf16(qf0, k0, s[nt]);
            s[nt] = mfma_bf16(qf1, k1, s[nt]);
        }

        // online softmax (rows = quad*4+r of this wave's stripe)
        float mx[4], al[4], rs[4];
#pragma unroll
        for (int r = 0; r < 4; ++r) {
            mx[r] = fmaxf(fmaxf(s[0][r], s[1][r]), fmaxf(s[2][r], s[3][r]));
#pragma unroll
            for (int off = 1; off < 16; off <<= 1)
                mx[r] = fmaxf(mx[r], __shfl_xor(mx[r], off, 64));
            float mnew = fmaxf(m_run[r], mx[r]);
            al[r] = __expf(m_run[r] - mnew);
            m_run[r] = mnew;
            rs[r] = 0.f;
        }
#pragma unroll
        for (int nt = 0; nt < 4; ++nt)
#pragma unroll
            for (int r = 0; r < 4; ++r) {
                float p = __expf(s[nt][r] - m_run[r]);
                s[nt][r] = p;
                rs[r] += p;
            }
#pragma unroll
        for (int r = 0; r < 4; ++r) {
#pragma unroll
            for (int off = 1; off < 16; off <<= 1)
                rs[r] += __shfl_xor(rs[r], off, 64);
            l_run[r] = l_run[r] * al[r] + rs[r];
        }
#pragma unroll
        for (int nt = 0; nt < 4; ++nt)
#pragma unroll
            for (int r = 0; r < 4; ++r) acco[nt][r] *= al[r];

        // P: C-layout -> LDS (f32, stride 68) -> A-layout frags (wave-local)
#pragma unroll
        for (int nt = 0; nt < 4; ++nt)
#pragma unroll
            for (int r = 0; r < 4; ++r)
                Pls[w][(quad * 4 + r) * 68 + nt * 16 + lrow] = s[nt][r];

#pragma unroll
        for (int ks = 0; ks < 2; ++ks) {
            f32x4 p0 = *(const f32x4*)&Pls[w][lrow * 68 + ks * 32 + quad * 8];
            f32x4 p1 = *(const f32x4*)&Pls[w][lrow * 68 + ks * 32 + quad * 8 + 4];
            bf16x8 pf;
            pf[0] = (__bf16)p0[0]; pf[1] = (__bf16)p0[1];
            pf[2] = (__bf16)p0[2]; pf[3] = (__bf16)p0[3];
            pf[4] = (__bf16)p1[0]; pf[5] = (__bf16)p1[1];
            pf[6] = (__bf16)p1[2]; pf[7] = (__bf16)p1[3];
#pragma unroll
            for (int nt = 0; nt < 4; ++nt) {
                bf16x8 vf = *(const bf16x8*)&Vls[(nt * 16 + lrow) * 64 + ks * 32 + quad * 8];
                acco[nt] = mfma_bf16(pf, vf, acco[nt]);
            }
        }
    }

    // O = acco / l, store bf16 to attn[b][n][h*64+d]
#pragma unroll
    for (int r = 0; r < 4; ++r) {
        float rl = 1.0f / l_run[r];
        int row = b * 2048 + q0 + w * 16 + quad * 4 + r;
#pragma unroll
        for (int nt = 0; nt < 4; ++nt)
            O[(size_t)row * 1024 + h * 64 + nt * 16 + lrow] = f2bfu(acco[nt][r] * rl);
    }
}

// ---------------- launch ----------------

extern "C" void kernel_launch(void* const* d_in, const int* in_sizes, int n_in,
                              void* d_out, int out_size, void* d_ws, size_t ws_size,
                              hipStream_t stream) {
    const float* x   = (const float*)d_in[0];
    const float* Wq  = (const float*)d_in[1];
    const float* Wkv = (const float*)d_in[2];
    const float* Wk1 = (const float*)d_in[3];
    const float* Wk2 = (const float*)d_in[4];
    const float* Wv1 = (const float*)d_in[5];
    const float* Wv2 = (const float*)d_in[6];
    const float* Wo  = (const float*)d_in[7];
    const float* bo  = (const float*)d_in[8];
    float* out = (float*)d_out;

    unsigned short* p = (unsigned short*)d_ws;
    unsigned short* xb    = p; p += 4194304;  // [4096][1024]
    unsigned short* WqT   = p; p += 1048576;  // [1024][1024]
    unsigned short* WkvT  = p; p += 2097152;  // [2048][1024]
    unsigned short* Wk1T  = p; p += 524288;   // [512][1024]
    unsigned short* Wk2T  = p; p += 524288;   // [1024][512]
    unsigned short* Wv1T  = p; p += 524288;   // [512][1024]
    unsigned short* Wv2T  = p; p += 524288;   // [1024][512]
    unsigned short* WoT   = p; p += 1048576;  // [1024][1024]
    unsigned short* qb    = p; p += 4194304;  // [4096][1024] (pre-scaled)
    unsigned short* kvb   = p; p += 8388608;  // [4096][2048]
    unsigned short* kb    = p; p += 4194304;  // [4096][1024]
    unsigned short* vb    = p; p += 4194304;  // [4096][1024]
    unsigned short* vtb   = p; p += 4194304;  // [32*64][2048]
    unsigned short* tmpb  = p; p += 2097152;  // [4096][512]
    unsigned short* attnb = p; p += 4194304;  // [4096][1024]

    dim3 blk(256);

    // prep: convert + transpose
    cvt_x_kernel<<<4096, blk, 0, stream>>>(x, xb);
    transpose_w_kernel<<<dim3(16, 16), blk, 0, stream>>>(Wq,  WqT,  1024, 1024);
    transpose_w_kernel<<<dim3(32, 16), blk, 0, stream>>>(Wkv, WkvT, 1024, 2048);
    transpose_w_kernel<<<dim3(8, 16),  blk, 0, stream>>>(Wk1, Wk1T, 1024, 512);
    transpose_w_kernel<<<dim3(16, 8),  blk, 0, stream>>>(Wk2, Wk2T, 512, 1024);
    transpose_w_kernel<<<dim3(8, 16),  blk, 0, stream>>>(Wv1, Wv1T, 1024, 512);
    transpose_w_kernel<<<dim3(16, 8),  blk, 0, stream>>>(Wv2, Wv2T, 512, 1024);
    transpose_w_kernel<<<dim3(16, 16), blk, 0, stream>>>(Wo,  WoT,  1024, 1024);

    // q = x @ Wq * 0.125  -> bf16
    gemm_bf16_kernel<<<dim3(8, 32), blk, 0, stream>>>(xb, 1024, WqT, 1024, qb, 1024, 1024, nullptr, 0.125f, 0, 0);
    // kv = x @ Wkv
    gemm_bf16_kernel<<<dim3(16, 32), blk, 0, stream>>>(xb, 1024, WkvT, 1024, kvb, 2048, 1024, nullptr, 1.f, 0, 0);
    // k1 = relu(kv[:, :1024] @ Wk1)
    gemm_bf16_kernel<<<dim3(4, 32), blk, 0, stream>>>(kvb, 2048, Wk1T, 1024, tmpb, 512, 1024, nullptr, 1.f, 1, 0);
    // k = k1 @ Wk2
    gemm_bf16_kernel<<<dim3(8, 32), blk, 0, stream>>>(tmpb, 512, Wk2T, 512, kb, 1024, 512, nullptr, 1.f, 0, 0);
    // v1 = relu(kv[:, 1024:] @ Wv1)
    gemm_bf16_kernel<<<dim3(4, 32), blk, 0, stream>>>(kvb + 1024, 2048, Wv1T, 1024, tmpb, 512, 1024, nullptr, 1.f, 1, 0);
    // v = v1 @ Wv2
    gemm_bf16_kernel<<<dim3(8, 32), blk, 0, stream>>>(tmpb, 512, Wv2T, 512, vb, 1024, 512, nullptr, 1.f, 0, 0);
    // Vt for attention
    transpose_v_kernel<<<dim3(32, 32), blk, 0, stream>>>(vb, vtb);
    // flash attention
    flash_mfma_kernel<<<dim3(32, 32), blk, 0, stream>>>(qb, kb, vtb, attnb);
    // out = attn @ Wo + bo  (fp32 out)
    gemm_bf16_kernel<<<dim3(8, 32), blk, 0, stream>>>(attnb, 1024, WoT, 1024, out, 1024, 1024, bo, 1.f, 0, 1);
}

// Round 5
// 355.220 us; speedup vs baseline: 4.2684x; 1.2299x over previous
//
#include <hip/hip_runtime.h>
#include <stdint.h>

// MLA bf16-MFMA pipeline R5 (= R4 with k2v2 ldb fix: Wk2T/Wv2T are [1024][512],
// row stride 512 — R4 passed 1024 and read past Wk2T into Wv2T).
// B=2, N=2048, D=1024, L=512, H=16, Dh=64.
// Flash K/V LDS in [2][64][32] half-tiles (kills 16-way bank conflicts),
// P roundtrip in bf16 (stride 72), softmax in log2 domain with 0.125*log2e
// folded into Wq^T; fused qkv GEMM, z-batched k1v1/k2v2 GEMMs, z-paired
// weight transposes (17 -> 11 launches).

typedef __attribute__((ext_vector_type(8))) __bf16 bf16x8;
typedef __attribute__((ext_vector_type(4))) float f32x4;

__device__ inline unsigned short f2bfu(float f) {
    __bf16 b = (__bf16)f;
    return __builtin_bit_cast(unsigned short, b);
}

__device__ inline float exp2_fast(float f) {
    return __builtin_amdgcn_exp2f(f);   // raw v_exp_f32
}

__device__ inline void load_lds16(const void* g, void* l) {
    __builtin_amdgcn_global_load_lds(
        (const __attribute__((address_space(1))) uint32_t*)g,
        (__attribute__((address_space(3))) uint32_t*)l, 16, 0, 0);
}

__device__ inline f32x4 mfma_bf16(bf16x8 a, bf16x8 b, f32x4 c) {
    return __builtin_amdgcn_mfma_f32_16x16x32_bf16(a, b, c, 0, 0, 0);
}

// ---------------- prep kernels ----------------

__global__ __launch_bounds__(256) void cvt_x_kernel(
    const float* __restrict__ src, unsigned short* __restrict__ dst)
{
    int i = (blockIdx.x * 256 + threadIdx.x) * 4;
    float4 v = *(const float4*)&src[i];
    ushort4 o;
    o.x = f2bfu(v.x); o.y = f2bfu(v.y); o.z = f2bfu(v.z); o.w = f2bfu(v.w);
    *(ushort4*)&dst[i] = o;
}

// z-batched: src f32 [R][C] -> dst bf16 [C][R] * scale. grid (C/64, R/64, nz)
__global__ __launch_bounds__(256) void transpose_w2_kernel(
    const float* __restrict__ s0, const float* __restrict__ s1,
    unsigned short* __restrict__ d0, unsigned short* __restrict__ d1,
    int R, int C, float sc0, float sc1)
{
    const float* src = blockIdx.z ? s1 : s0;
    unsigned short* dst = blockIdx.z ? d1 : d0;
    float sc = blockIdx.z ? sc1 : sc0;
    __shared__ float tile[64][65];
    int c0 = blockIdx.x * 64, r0 = blockIdx.y * 64;
    int t = threadIdx.x;
    int col = t & 63, rr = t >> 6;
#pragma unroll
    for (int i = 0; i < 16; ++i)
        tile[rr + i * 4][col] = src[(size_t)(r0 + rr + i * 4) * C + c0 + col];
    __syncthreads();
#pragma unroll
    for (int i = 0; i < 16; ++i) {
        int r2 = rr + i * 4;
        dst[(size_t)(c0 + r2) * R + r0 + col] = f2bfu(tile[col][r2] * sc);
    }
}

// v[b][n][h*64+d] (ld ldv) bf16 -> vt[(b*16+h)*64+d][n]. grid (2048/64, 32)
__global__ __launch_bounds__(256) void transpose_v_kernel(
    const unsigned short* __restrict__ v, int ldv, unsigned short* __restrict__ vt)
{
    __shared__ unsigned short tile[64][65];
    int n0 = blockIdx.x * 64, bh = blockIdx.y;
    int b = bh >> 4, h = bh & 15;
    int t = threadIdx.x;
    int r = t >> 3, c = t & 7;
#pragma unroll
    for (int p = 0; p < 2; ++p) {
        int row = r + p * 32;
        const unsigned short* src = v + (size_t)(b * 2048 + n0 + row) * ldv + h * 64 + c * 8;
        ushort4 a = *(const ushort4*)src;
        ushort4 b4 = *(const ushort4*)(src + 4);
        tile[row][c * 8 + 0] = a.x;  tile[row][c * 8 + 1] = a.y;
        tile[row][c * 8 + 2] = a.z;  tile[row][c * 8 + 3] = a.w;
        tile[row][c * 8 + 4] = b4.x; tile[row][c * 8 + 5] = b4.y;
        tile[row][c * 8 + 6] = b4.z; tile[row][c * 8 + 7] = b4.w;
    }
    __syncthreads();
#pragma unroll
    for (int p = 0; p < 2; ++p) {
        int d = r + p * 32;
        ushort4 o0, o1;
        o0.x = tile[c * 8 + 0][d]; o0.y = tile[c * 8 + 1][d];
        o0.z = tile[c * 8 + 2][d]; o0.w = tile[c * 8 + 3][d];
        o1.x = tile[c * 8 + 4][d]; o1.y = tile[c * 8 + 5][d];
        o1.z = tile[c * 8 + 6][d]; o1.w = tile[c * 8 + 7][d];
        unsigned short* dp = vt + (size_t)(bh * 64 + d) * 2048 + n0 + c * 8;
        *(ushort4*)dp = o0;
        *(ushort4*)(dp + 4) = o1;
    }
}

// ---------------- bf16 MFMA GEMM (m97 structure, z-batched) ----------------
// C[M][N] = A[M][K] @ Bt[N][K]^T (+bias)(relu). 128x128 tile, BK=32.
// grid (N/128, M/128, nz), block 256.
__global__ __launch_bounds__(256) void gemm_bf16_kernel(
    const unsigned short* __restrict__ A0, const unsigned short* __restrict__ A1,
    const unsigned short* __restrict__ B0, const unsigned short* __restrict__ B1,
    void* __restrict__ C0, void* __restrict__ C1,
    int lda, int ldb, int ldc, int K,
    const float* __restrict__ bias, int relu, int out_f32)
{
    const unsigned short* A = blockIdx.z ? A1 : A0;
    const unsigned short* Bt = blockIdx.z ? B1 : B0;
    void* C = blockIdx.z ? C1 : C0;

    __shared__ unsigned short Als[128 * 32];
    __shared__ unsigned short Bls[128 * 32];
    int t = threadIdx.x;
    int lane = t & 63, w = t >> 6;
    int n0 = blockIdx.x * 128, m0 = blockIdx.y * 128;
    int wm = (w & 1) * 64, wn = (w >> 1) * 64;
    int lrow = lane & 15, quad = lane >> 4;

    f32x4 acc[4][4];
    f32x4 z = {0.f, 0.f, 0.f, 0.f};
#pragma unroll
    for (int i = 0; i < 4; ++i)
#pragma unroll
        for (int j = 0; j < 4; ++j) acc[i][j] = z;

    int c0 = t, c1 = t + 256;
    const unsigned short* ag0 = A + (size_t)(m0 + (c0 >> 2)) * lda + (c0 & 3) * 8;
    const unsigned short* ag1 = A + (size_t)(m0 + (c1 >> 2)) * lda + (c1 & 3) * 8;
    const unsigned short* bg0 = Bt + (size_t)(n0 + (c0 >> 2)) * ldb + (c0 & 3) * 8;
    const unsigned short* bg1 = Bt + (size_t)(n0 + (c1 >> 2)) * ldb + (c1 & 3) * 8;

    for (int k0 = 0; k0 < K; k0 += 32) {
        __syncthreads();
        load_lds16(ag0 + k0, &Als[c0 * 8]);
        load_lds16(ag1 + k0, &Als[c1 * 8]);
        load_lds16(bg0 + k0, &Bls[c0 * 8]);
        load_lds16(bg1 + k0, &Bls[c1 * 8]);
        __syncthreads();

        bf16x8 af[4], bfr[4];
#pragma unroll
        for (int mi = 0; mi < 4; ++mi)
            af[mi] = *(const bf16x8*)&Als[(wm + mi * 16 + lrow) * 32 + quad * 8];
#pragma unroll
        for (int ni = 0; ni < 4; ++ni)
            bfr[ni] = *(const bf16x8*)&Bls[(wn + ni * 16 + lrow) * 32 + quad * 8];
#pragma unroll
        for (int mi = 0; mi < 4; ++mi)
#pragma unroll
            for (int ni = 0; ni < 4; ++ni)
                acc[mi][ni] = mfma_bf16(af[mi], bfr[ni], acc[mi][ni]);
    }

#pragma unroll
    for (int mi = 0; mi < 4; ++mi)
#pragma unroll
        for (int ni = 0; ni < 4; ++ni)
#pragma unroll
            for (int r = 0; r < 4; ++r) {
                int row = m0 + wm + mi * 16 + quad * 4 + r;
                int col = n0 + wn + ni * 16 + lrow;
                float v = acc[mi][ni][r];
                if (bias) v += bias[col];
                if (relu) v = fmaxf(v, 0.0f);
                if (out_f32) ((float*)C)[(size_t)row * ldc + col] = v;
                else ((unsigned short*)C)[(size_t)row * ldc + col] = f2bfu(v);
            }
}

// ---------------- MFMA flash attention ----------------
// Q (ldq, scaled by 0.125*log2e), K (ldk): head-interleaved; Vt [32*64][2048].
// grid (2048/64, 32), block 256 (4 waves). Wave w owns Q rows w*16..+15.
// Softmax in log2 domain (exp2 -> raw v_exp_f32).
__global__ __launch_bounds__(256) void flash_mfma_kernel(
    const unsigned short* __restrict__ Q, int ldq,
    const unsigned short* __restrict__ K, int ldk,
    const unsigned short* __restrict__ Vt, unsigned short* __restrict__ O)
{
    __shared__ unsigned short Kls[2 * 64 * 32];  // [half d][kv row][32 d]
    __shared__ unsigned short Vls[2 * 64 * 32];  // [half kv][d row][32 kv]
    __shared__ unsigned short Pls[4][16 * 72];   // per-wave, stride 72 (16B-aligned rows)

    int q0 = blockIdx.x * 64, bh = blockIdx.y;
    int b = bh >> 4, h = bh & 15;
    int t = threadIdx.x;
    int lane = t & 63, w = t >> 6;
    int lrow = lane & 15, quad = lane >> 4;

    const unsigned short* qrow = Q + (size_t)(b * 2048 + q0 + w * 16 + lrow) * ldq + h * 64;
    bf16x8 qf0 = *(const bf16x8*)&qrow[quad * 8];
    bf16x8 qf1 = *(const bf16x8*)&qrow[32 + quad * 8];

    f32x4 z = {0.f, 0.f, 0.f, 0.f};
    f32x4 acco[4];
#pragma unroll
    for (int i = 0; i < 4; ++i) acco[i] = z;
    float m_run[4] = {-1e30f, -1e30f, -1e30f, -1e30f};
    float l_run[4] = {0.f, 0.f, 0.f, 0.f};

    // staging: thread t covers row t>>2, d/kv segment (t&3)*8 of each half
    int row4 = t >> 2;
    int seg = (t & 3) * 8;
    const unsigned short* kg = K + (size_t)(b * 2048 + row4) * ldk + h * 64 + seg;
    const unsigned short* vg = Vt + (size_t)(bh * 64 + row4) * 2048 + seg;

    for (int kt = 0; kt < 2048; kt += 64) {
        __syncthreads();
        const unsigned short* kgk = kg + (size_t)kt * ldk;
        load_lds16(kgk,      &Kls[t * 8]);
        load_lds16(kgk + 32, &Kls[2048 + t * 8]);
        load_lds16(vg + kt,      &Vls[t * 8]);
        load_lds16(vg + kt + 32, &Vls[2048 + t * 8]);
        __syncthreads();

        // S = Q K^T : 16 q rows x 64 kv
        f32x4 s[4];
#pragma unroll
        for (int nt = 0; nt < 4; ++nt) {
            bf16x8 k0 = *(const bf16x8*)&Kls[(nt * 16 + lrow) * 32 + quad * 8];
            bf16x8 k1 = *(const bf16x8*)&Kls[2048 + (nt * 16 + lrow) * 32 + quad * 8];
            s[nt] = mfma_bf16(qf0, k0, z);
            s[nt] = mfma_bf16(qf1, k1, s[nt]);
        }

        // online softmax, log2 domain
        float mx[4], al[4], rs[4];
#pragma unroll
        for (int r = 0; r < 4; ++r) {
            mx[r] = fmaxf(fmaxf(s[0][r], s[1][r]), fmaxf(s[2][r], s[3][r]));
#pragma unroll
            for (int off = 1; off < 16; off <<= 1)
                mx[r] = fmaxf(mx[r], __shfl_xor(mx[r], off, 64));
            float mnew = fmaxf(m_run[r], mx[r]);
            al[r] = exp2_fast(m_run[r] - mnew);
            m_run[r] = mnew;
            rs[r] = 0.f;
        }
#pragma unroll
        for (int nt = 0; nt < 4; ++nt)
#pragma unroll
            for (int r = 0; r < 4; ++r) {
                float p = exp2_fast(s[nt][r] - m_run[r]);
                s[nt][r] = p;
                rs[r] += p;
            }
#pragma unroll
        for (int r = 0; r < 4; ++r) {
#pragma unroll
            for (int off = 1; off < 16; off <<= 1)
                rs[r] += __shfl_xor(rs[r], off, 64);
            l_run[r] = l_run[r] * al[r] + rs[r];
        }
#pragma unroll
        for (int nt = 0; nt < 4; ++nt)
#pragma unroll
            for (int r = 0; r < 4; ++r) acco[nt][r] *= al[r];

        // P: C-layout -> bf16 LDS -> A-layout frags (wave-local, no barrier)
#pragma unroll
        for (int nt = 0; nt < 4; ++nt)
#pragma unroll
            for (int r = 0; r < 4; ++r)
                Pls[w][(quad * 4 + r) * 72 + nt * 16 + lrow] = f2bfu(s[nt][r]);

#pragma unroll
        for (int ks = 0; ks < 2; ++ks) {
            bf16x8 pf = *(const bf16x8*)&Pls[w][lrow * 72 + ks * 32 + quad * 8];
#pragma unroll
            for (int nt = 0; nt < 4; ++nt) {
                bf16x8 vf = *(const bf16x8*)&Vls[ks * 2048 + (nt * 16 + lrow) * 32 + quad * 8];
                acco[nt] = mfma_bf16(pf, vf, acco[nt]);
            }
        }
    }

#pragma unroll
    for (int r = 0; r < 4; ++r) {
        float rl = 1.0f / l_run[r];
        int row = b * 2048 + q0 + w * 16 + quad * 4 + r;
#pragma unroll
        for (int nt = 0; nt < 4; ++nt)
            O[(size_t)row * 1024 + h * 64 + nt * 16 + lrow] = f2bfu(acco[nt][r] * rl);
    }
}

// ---------------- launch ----------------

extern "C" void kernel_launch(void* const* d_in, const int* in_sizes, int n_in,
                              void* d_out, int out_size, void* d_ws, size_t ws_size,
                              hipStream_t stream) {
    const float* x   = (const float*)d_in[0];
    const float* Wq  = (const float*)d_in[1];
    const float* Wkv = (const float*)d_in[2];
    const float* Wk1 = (const float*)d_in[3];
    const float* Wk2 = (const float*)d_in[4];
    const float* Wv1 = (const float*)d_in[5];
    const float* Wv2 = (const float*)d_in[6];
    const float* Wo  = (const float*)d_in[7];
    const float* bo  = (const float*)d_in[8];
    float* out = (float*)d_out;

    unsigned short* p = (unsigned short*)d_ws;
    unsigned short* xb    = p; p += 4194304;   // [4096][1024]
    unsigned short* WqkvT = p; p += 3145728;   // [3072][1024]  (Wq^T scaled | Wkv^T)
    unsigned short* WoT   = p; p += 1048576;   // [1024][1024]
    unsigned short* Wk1T  = p; p += 524288;    // [512][1024]
    unsigned short* Wv1T  = p; p += 524288;    // [512][1024]
    unsigned short* Wk2T  = p; p += 524288;    // [1024][512]
    unsigned short* Wv2T  = p; p += 524288;    // [1024][512]
    unsigned short* qkv   = p; p += 12582912;  // [4096][3072]  (q | k-in | v-in)
    unsigned short* tmpb  = p; p += 4194304;   // [4096][1024]  (k1 | v1), reused as attn
    unsigned short* kvo   = p; p += 8388608;   // [4096][2048]  (k | v)
    unsigned short* vtb   = p; p += 4194304;   // [32*64][2048]
    unsigned short* attnb = tmpb;              // alias: tmp dead after k2v2

    dim3 blk(256);
    const float qscale = 0.125f * 1.44269504f;  // Dh^-0.5 * log2(e)

    cvt_x_kernel<<<4096, blk, 0, stream>>>(x, xb);
    transpose_w2_kernel<<<dim3(16, 16, 2), blk, 0, stream>>>(Wq, Wo, WqkvT, WoT, 1024, 1024, qscale, 1.0f);
    transpose_w2_kernel<<<dim3(32, 16, 1), blk, 0, stream>>>(Wkv, Wkv, WqkvT + 1048576, WqkvT + 1048576, 1024, 2048, 1.0f, 1.0f);
    transpose_w2_kernel<<<dim3(8, 16, 2),  blk, 0, stream>>>(Wk1, Wv1, Wk1T, Wv1T, 1024, 512, 1.0f, 1.0f);
    transpose_w2_kernel<<<dim3(16, 8, 2),  blk, 0, stream>>>(Wk2, Wv2, Wk2T, Wv2T, 512, 1024, 1.0f, 1.0f);

    // qkv = x @ [Wq*s | Wkv]   -> qkv [4096][3072]
    gemm_bf16_kernel<<<dim3(24, 32, 1), blk, 0, stream>>>(
        xb, xb, WqkvT, WqkvT, qkv, qkv, 1024, 1024, 3072, 1024, nullptr, 0, 0);
    // k1 = relu(kv_k @ Wk1), v1 = relu(kv_v @ Wv1)  -> tmpb [4096][512|512]
    gemm_bf16_kernel<<<dim3(4, 32, 2), blk, 0, stream>>>(
        qkv + 1024, qkv + 2048, Wk1T, Wv1T, tmpb, tmpb + 512,
        3072, 1024, 1024, 1024, nullptr, 1, 0);
    // k = k1 @ Wk2, v = v1 @ Wv2  -> kvo [4096][1024|1024]   (ldb = 512!)
    gemm_bf16_kernel<<<dim3(8, 32, 2), blk, 0, stream>>>(
        tmpb, tmpb + 512, Wk2T, Wv2T, kvo, kvo + 1024,
        1024, 512, 2048, 512, nullptr, 0, 0);

    transpose_v_kernel<<<dim3(32, 32), blk, 0, stream>>>(kvo + 1024, 2048, vtb);
    flash_mfma_kernel<<<dim3(32, 32), blk, 0, stream>>>(qkv, 3072, kvo, 2048, vtb, attnb);
    // out = attn @ Wo + bo (fp32)
    gemm_bf16_kernel<<<dim3(8, 32, 1), blk, 0, stream>>>(
        attnb, attnb, WoT, WoT, out, out, 1024, 1024, 1024, 1024, bo, 0, 1);
}